// Round 3
// baseline (1851.135 us; speedup 1.0000x reference)
//
#include <hip/hip_runtime.h>

// GPUHungarianMatcher — exact replication of the reference's degenerate "_lsa"
// (minv reset every iteration => chain-Dijkstra), one WAVE per batch.
//
// Key structural facts exploited:
//  * Within one row-search, scans read only PRE-search u/v (each visited row/col
//    is new, so its potential hasn't changed yet) => defer all potential updates
//    to search end: O(path) work instead of O(m) per step.
//  * Single wave => no __syncthreads in the step loop; argmin via shuffle
//    butterfly; v[] lives in registers (32 cols/lane, q = lane + 64k).
//  * f64 semantics identical to reference: ((double)cf - u[i0]) - v[j],
//    strict-< keeps smallest j on exact ties (np.argmin first-occurrence).
//  * Softmax bitwise-replicates the R2-passing version: lane partials split by
//    k mod 4 equal R2's 256-thread partials; same shuffle tree; same final
//    ((w0+w1)+w2)+w3 order; fmax is order-independent.

constexpr int B = 8;
constexpr int Q = 2048;        // columns (queries)
constexpr int T = 256;         // rows (targets)
constexpr int NL = 64;         // one wave per block
constexpr int KPL = Q / NL;    // 32 columns per lane, q = lane + 64*k
constexpr double DINF = 1e300;

__launch_bounds__(NL, 1)
__global__ void hungarian_wave(const float* __restrict__ outs,
                               const float* __restrict__ tgts,
                               int* __restrict__ out) {
  const int b = blockIdx.x;
  const int lane = threadIdx.x;

  __shared__ float tx[T], ty[T];
  __shared__ double u[T + 1];        // row potentials
  __shared__ short p[Q + 1];         // p[j]: row matched to col j (1-based), 0 free
  __shared__ short visCol[Q + 4];    // visit chain: visCol[0]=0, visCol[s]=col of step s
  __shared__ short visRow[Q + 4];    // pre-augment rows p[visCol[s]]
  __shared__ double visD[Q + 4];     // delta prefix sums (before step s)
  __shared__ int ansArr[T];

  const size_t qbase = (size_t)b * Q;
  const size_t tbase = (size_t)b * T;

  // ---- stage per-lane column data, q = lane + 64*k ----
  float xs[KPL], qx[KPL], qy[KPL];
#pragma unroll
  for (int k = 0; k < KPL; ++k) {
    const size_t o = (qbase + lane + k * NL) * 3;
    xs[k] = outs[o];
    qx[k] = outs[o + 1];
    qy[k] = outs[o + 2];
  }
  for (int t = lane; t < T; t += NL) {
    const size_t o = (tbase + t) * 3;
    tx[t] = tgts[o + 1];
    ty[t] = tgts[o + 2];
  }

  // ---- softmax (bitwise-matches the R2-passing computation) ----
  float lmax = xs[0];
#pragma unroll
  for (int k = 1; k < KPL; ++k) lmax = fmaxf(lmax, xs[k]);
  for (int off = 32; off > 0; off >>= 1) lmax = fmaxf(lmax, __shfl_xor(lmax, off));
  float ex[KPL];
#pragma unroll
  for (int k = 0; k < KPL; ++k) ex[k] = expf(xs[k] - lmax);
  // R2 thread t = lane + 64w summed q = t + 256*k8  ->  local k = w + 4*k8
  float ssum;
  {
    float ws[4];
#pragma unroll
    for (int w = 0; w < 4; ++w) {
      float pw = ex[w];
#pragma unroll
      for (int k8 = 1; k8 < 8; ++k8) pw += ex[w + 4 * k8];
      for (int off = 32; off > 0; off >>= 1) pw += __shfl_down(pw, off);
      ws[w] = __shfl(pw, 0);   // R2's per-wave partial, exact tree
    }
    ssum = ((ws[0] + ws[1]) + ws[2]) + ws[3];   // R2's serial order
  }
  float np_[KPL];
#pragma unroll
  for (int k = 0; k < KPL; ++k) np_[k] = -(ex[k] / ssum);

  // ---- init JV state ----
  for (int j = lane; j <= Q; j += NL) p[j] = 0;
  for (int r = lane; r <= T; r += NL) u[r] = 0.0;
  double vreg[KPL];
#pragma unroll
  for (int k = 0; k < KPL; ++k) vreg[k] = 0.0;
  __syncthreads();

  // ---- main loop over rows ----
  for (int i = 1; i <= T; ++i) {
    if (lane == 0) { p[0] = (short)i; visCol[0] = 0; }
    unsigned usedMask = 0;
    double D = 0.0;            // cumulative delta
    int i0 = i;
    __syncthreads();
    double ui0 = u[i0];
    float tX = tx[i0 - 1], tY = ty[i0 - 1];
    int s = 0, S;

    for (;;) {
      if (lane == 0) visD[s] = D;      // prefix (deltas of steps < s)

      // scan my 32 unused columns: cur = ((double)cf - u[i0]) - v[j]
      double bval = DINF;
      int bidx = 0x7fffffff;
#pragma unroll
      for (int k = 0; k < KPL; ++k) {
        const float cf = fabsf(qx[k] - tX) + fabsf(qy[k] - tY) + np_[k];
        const double cur = ((double)cf - ui0) - vreg[k];
        const bool avail = !((usedMask >> k) & 1u);
        if (avail && (cur < bval)) { bval = cur; bidx = lane + (k << 6); }
      }
      // butterfly lexicographic argmin (value, then smallest q) — all lanes converge
      for (int off = 32; off > 0; off >>= 1) {
        const double ov = __shfl_xor(bval, off);
        const int oi = __shfl_xor(bidx, off);
        if (ov < bval || (ov == bval && oi < bidx)) { bval = ov; bidx = oi; }
      }

      D += bval;                        // delta
      const int q1 = bidx;              // 0-based selected column
      if ((q1 & 63) == lane) usedMask |= 1u << (q1 >> 6);
      if (lane == 0) visCol[s + 1] = (short)(q1 + 1);
      const int pj1 = (int)p[q1 + 1];   // stable during search (augment deferred)
      ++s;
      if (pj1 == 0) { S = s; break; }
      i0 = pj1;
      ui0 = u[i0];
      tX = tx[i0 - 1]; tY = ty[i0 - 1];
    }

    // ---- deferred updates, O(path) ----
    __syncthreads();
    const double Dfin = D;
    // phase 1: snapshot pre-augment rows
    for (int sb = lane; sb < S; sb += NL) visRow[sb] = p[(int)visCol[sb]];
    __syncthreads();
    // phase 2: u[row_s] += Dfin - visD[s]; augment p[visCol[s+1]] = visRow[s]
    // (rows and cols in the visit chain are distinct => race-free)
    for (int sb = lane; sb < S; sb += NL) {
      u[(int)visRow[sb]] += Dfin - visD[sb];
      p[(int)visCol[sb + 1]] = visRow[sb];
    }
    // v updates for used cols visCol[1..S-1] (owner lane applies; uniform reads)
    for (int sv = 1; sv < S; ++sv) {
      const int qv = (int)visCol[sv] - 1;
      if ((qv & 63) == lane) vreg[qv >> 6] -= Dfin - visD[sv];
    }
    __syncthreads();
  }

  // ---- extract assignment, rank-sort (distinct values), write int32 ----
  for (int j = 1 + lane; j <= Q; j += NL) {
    const int pi = (int)p[j];
    if (pi > 0) ansArr[pi - 1] = j - 1;
  }
  __syncthreads();
#pragma unroll
  for (int w = 0; w < 4; ++w) {
    const int t = lane + 64 * w;
    const int a = ansArr[t];
    int rank = 0;
    for (int t2 = 0; t2 < T; ++t2) rank += (ansArr[t2] < a) ? 1 : 0;
    out[(size_t)b * T + rank] = a;                      // row_ind (sorted query idx)
    out[(size_t)B * T + (size_t)b * T + rank] = t;      // col_ind (target idx)
  }
}

extern "C" void kernel_launch(void* const* d_in, const int* in_sizes, int n_in,
                              void* d_out, int out_size, void* d_ws, size_t ws_size,
                              hipStream_t stream) {
  const float* outs = (const float*)d_in[0];   // (8, 2048, 3) fp32
  const float* tgts = (const float*)d_in[1];   // (8, 256, 3) fp32
  int* out = (int*)d_out;                      // row_ind (8,256) ++ col_ind (8,256)
  hungarian_wave<<<B, NL, 0, stream>>>(outs, tgts, out);
}

// Round 4
// 1355.233 us; speedup vs baseline: 1.3659x; 1.3659x over previous
//
#include <hip/hip_runtime.h>

// GPUHungarianMatcher — exact replication of the reference's degenerate "_lsa"
// (minv reset every inner iteration => chain-Dijkstra). One block (4 waves)
// per batch. R4 = R2's 4-wave scan parallelism + R3's deferred O(path)
// potential updates + single barrier per step (parity-double-buffered
// partials, redundant final reduce on all threads).
//
// Exactness invariants (validated by R2/R3 passing with absmax 0):
//  * cost fp32: fabsf(qx-tX)+fabsf(qy-tY)+np_, reduced fp64: ((double)cf-u)-v
//  * scans read only PRE-search u/v (path rows/cols distinct) => defer updates
//  * argmin: strict <, ascending j => np.argmin first-occurrence tie-break
//  * softmax bitwise-identical to the R2 tree (same thread mapping)

constexpr int B = 8;
constexpr int Q = 2048;        // columns (queries)
constexpr int T = 256;         // rows (targets)
constexpr int NT = 256;        // threads per block (4 waves)
constexpr int KPT = Q / NT;    // 8 columns per thread, j = 1 + tid + k*256
constexpr int NW = NT / 64;
constexpr double DINF = 1e300;

struct RowDat { float tx, ty; double u; };   // 16 B => single ds_read_b128

__launch_bounds__(NT, 1)
__global__ void hungarian_hybrid(const float* __restrict__ outs,
                                 const float* __restrict__ tgts,
                                 int* __restrict__ out) {
  const int b = blockIdx.x;
  const int tid = threadIdx.x;
  const int lane = tid & 63;
  const int wv = tid >> 6;

  __shared__ RowDat rd[T + 1];      // rd[r] = {tx[r-1], ty[r-1], u[r]}
  __shared__ short p[Q + 1];        // p[j]: row matched to col j (1-based), 0 free
  __shared__ short visCol[Q + 4];   // visit chain: visCol[0]=0
  __shared__ short visRow[Q + 4];   // pre-augment rows p[visCol[s]]
  __shared__ double visD[Q + 4];    // delta prefix sums (before step s)
  __shared__ double pv[2][NW];      // per-wave partial min values (parity-buffered)
  __shared__ int pidx[2][NW];       // per-wave partial argmin (j, 1-based)
  __shared__ int ansArr[T];
  __shared__ double s_rv[NW];
  __shared__ float sh_f;

  const size_t qbase = (size_t)b * Q;
  const size_t tbase = (size_t)b * T;

  // ---- stage per-thread column data (fixed mapping j = 1 + tid + k*256) ----
  float xs[KPT], qx[KPT], qy[KPT];
#pragma unroll
  for (int k = 0; k < KPT; ++k) {
    const size_t o = (qbase + tid + k * NT) * 3;
    xs[k] = outs[o];
    qx[k] = outs[o + 1];
    qy[k] = outs[o + 2];
  }
  {
    const size_t o = (tbase + tid) * 3;   // T == NT: one target per thread
    rd[tid + 1].tx = tgts[o + 1];
    rd[tid + 1].ty = tgts[o + 2];
    rd[tid + 1].u = 0.0;
    if (tid == 0) { rd[0].tx = 0.f; rd[0].ty = 0.f; rd[0].u = 0.0; }
  }

  // ---- softmax over Q logits (bitwise-identical to the R2-passing tree) ----
  float lmax = xs[0];
#pragma unroll
  for (int k = 1; k < KPT; ++k) lmax = fmaxf(lmax, xs[k]);
  for (int off = 32; off > 0; off >>= 1) lmax = fmaxf(lmax, __shfl_down(lmax, off));
  if ((tid & 63) == 0) s_rv[tid >> 6] = (double)lmax;
  __syncthreads();
  if (tid == 0) {
    float m2 = (float)s_rv[0];
    for (int w = 1; w < NW; ++w) m2 = fmaxf(m2, (float)s_rv[w]);
    sh_f = m2;
  }
  __syncthreads();
  const float smax = sh_f;
  float ex[KPT];
  float lsum = 0.f;
#pragma unroll
  for (int k = 0; k < KPT; ++k) { ex[k] = expf(xs[k] - smax); lsum += ex[k]; }
  for (int off = 32; off > 0; off >>= 1) lsum += __shfl_down(lsum, off);
  if ((tid & 63) == 0) s_rv[tid >> 6] = (double)lsum;
  __syncthreads();
  if (tid == 0) {
    float s2 = 0.f;
    for (int w = 0; w < NW; ++w) s2 += (float)s_rv[w];
    sh_f = s2;
  }
  __syncthreads();
  const float ssum = sh_f;
  float np_[KPT];
#pragma unroll
  for (int k = 0; k < KPT; ++k) np_[k] = -(ex[k] / ssum);

  // ---- init state ----
  for (int j = tid; j <= Q; j += NT) p[j] = 0;
  double vreg[KPT];   // v[j] for this thread's 8 columns
#pragma unroll
  for (int k = 0; k < KPT; ++k) vreg[k] = 0.0;
  __syncthreads();

  // ---- main loop over rows ----
  for (int i = 1; i <= T; ++i) {
    if (tid == 0) p[0] = (short)i;
    unsigned usedMask = 0;
    double D = 0.0;
    int i0 = i;
    __syncthreads();            // Bs: prev search's p/u writes drained
    RowDat r0 = rd[i0];
    double ui0 = r0.u;
    float tX = r0.tx, tY = r0.ty;
    int s = 0, S;

    for (;;) {
      // scan my 8 unused columns: cur = ((double)cf - u[i0]) - v[j]
      double bval = DINF;
      int bidx = 0x7fffffff;
#pragma unroll
      for (int k = 0; k < KPT; ++k) {
        const float cf = fabsf(qx[k] - tX) + fabsf(qy[k] - tY) + np_[k];
        double cur = ((double)cf - ui0) - vreg[k];
        if (usedMask & (1u << k)) cur = DINF;   // used => never wins strict <
        if (cur < bval) { bval = cur; bidx = 1 + tid + (k << 8); }
      }
      // wave butterfly lexicographic argmin (value, then smallest j)
      for (int off = 32; off > 0; off >>= 1) {
        const double ov = __shfl_xor(bval, off);
        const int oi = __shfl_xor(bidx, off);
        if (ov < bval || (ov == bval && oi < bidx)) { bval = ov; bidx = oi; }
      }
      const int par = s & 1;
      if (lane == 0) { pv[par][wv] = bval; pidx[par][wv] = bidx; }
      if (tid == 0) visD[s] = D;   // prefix (deltas of steps < s)
      __syncthreads();            // B1 — the only per-step barrier
      // redundant final reduce on ALL threads (LDS broadcast reads)
      double dv = pv[par][0];
      int di = pidx[par][0];
#pragma unroll
      for (int w = 1; w < NW; ++w) {
        const double ov = pv[par][w];
        const int oi = pidx[par][w];
        if (ov < dv || (ov == dv && oi < di)) { dv = ov; di = oi; }
      }
      D += dv;
      const int j1 = di;          // selected column, 1-based
      if (tid == ((j1 - 1) & 255)) usedMask |= 1u << ((j1 - 1) >> 8);
      if (tid == 0) visCol[s + 1] = (short)j1;
      const int pj1 = (int)p[j1]; // stable during search (augment deferred)
      ++s;
      if (pj1 == 0) { S = s; break; }
      i0 = pj1;
      const RowDat rr = rd[i0];   // one b128 load: u, tx, ty together
      ui0 = rr.u; tX = rr.tx; tY = rr.ty;
    }

    // ---- deferred updates, O(path) ----
    __syncthreads();              // B2: visD/visCol visible; pv reads done
    const double Dfin = D;
    for (int sb = tid; sb < S; sb += NT) visRow[sb] = p[(int)visCol[sb]];
    __syncthreads();              // B3
    // u[row_s] += Dfin - visD[s]; augment p[visCol[s+1]] = visRow[s]
    // (path rows and cols distinct => race-free)
    for (int sb = tid; sb < S; sb += NT) {
      rd[(int)visRow[sb]].u += Dfin - visD[sb];
      p[(int)visCol[sb + 1]] = visRow[sb];
    }
    // v updates for used cols visCol[1..S-1] (owner thread applies)
    for (int sv = 1; sv < S; ++sv) {
      const int qv = (int)visCol[sv] - 1;
      if ((qv & 255) == tid) vreg[qv >> 8] -= Dfin - visD[sv];
    }
    // next Bs barrier orders these writes before the next search's reads
  }
  __syncthreads();

  // ---- extract assignment, rank-sort (distinct values), write int32 ----
  for (int j = 1 + tid; j <= Q; j += NT) {
    const int pi = (int)p[j];
    if (pi > 0) ansArr[pi - 1] = j - 1;
  }
  __syncthreads();
  const int a = ansArr[tid];
  int rank = 0;
  for (int t2 = 0; t2 < T; ++t2) rank += (ansArr[t2] < a) ? 1 : 0;
  out[(size_t)b * T + rank] = a;                      // row_ind (sorted query idx)
  out[(size_t)B * T + (size_t)b * T + rank] = tid;    // col_ind (target idx)
}

extern "C" void kernel_launch(void* const* d_in, const int* in_sizes, int n_in,
                              void* d_out, int out_size, void* d_ws, size_t ws_size,
                              hipStream_t stream) {
  const float* outs = (const float*)d_in[0];   // (8, 2048, 3) fp32
  const float* tgts = (const float*)d_in[1];   // (8, 256, 3) fp32
  int* out = (int*)d_out;                      // row_ind (8,256) ++ col_ind (8,256)
  hungarian_hybrid<<<B, NT, 0, stream>>>(outs, tgts, out);
}

// Round 5
// 1026.622 us; speedup vs baseline: 1.8031x; 1.3201x over previous
//
#include <hip/hip_runtime.h>

// GPUHungarianMatcher — exact replication of the reference's degenerate "_lsa"
// (minv reset every inner iteration => chain-Dijkstra). One block (4 waves)
// per batch. R5 = R4 + DPP-based wave argmin (u32 hi-key fast path, exact
// tie slow path) + column-indexed row-data cache (parallel p/colDat reads)
// + register-snapshot augment.
//
// Exactness invariants (validated by R2-R4 passing with absmax 0):
//  * cost fp32: fabsf(qx-tX)+fabsf(qy-tY)+np_, reduced fp64: ((double)cf-u)-v
//  * scans read only PRE-search u/v (path rows/cols distinct) => defer updates
//  * argmin: strict <, ascending j => np.argmin first-occurrence tie-break
//    (f64 < handles -0.0==+0.0; bit-key path canonicalizes winner with +0.0)
//  * softmax bitwise-identical to the R2 tree (same thread mapping)

constexpr int B = 8;
constexpr int Q = 2048;        // columns (queries)
constexpr int T = 256;         // rows (targets)
constexpr int NT = 256;        // threads per block (4 waves)
constexpr int KPT = Q / NT;    // 8 columns per thread, j = 1 + tid + k*256
constexpr int NW = NT / 64;
constexpr double DINF = 1e300;

struct __align__(16) CD { double u; float tx, ty; };   // one ds_read_b128

__device__ __forceinline__ unsigned wave_min_u32_dpp(unsigned a) {
  // full-wave u32 min: row_shr 1,2,4,8 then row_bcast15, row_bcast31;
  // invalid source lanes keep old (bound_ctrl=false, masks 0xf) = identity.
  int v = (int)a, t;
  t = __builtin_amdgcn_update_dpp(v, v, 0x111, 0xf, 0xf, false);
  v = ((unsigned)t < (unsigned)v) ? t : v;
  t = __builtin_amdgcn_update_dpp(v, v, 0x112, 0xf, 0xf, false);
  v = ((unsigned)t < (unsigned)v) ? t : v;
  t = __builtin_amdgcn_update_dpp(v, v, 0x114, 0xf, 0xf, false);
  v = ((unsigned)t < (unsigned)v) ? t : v;
  t = __builtin_amdgcn_update_dpp(v, v, 0x118, 0xf, 0xf, false);
  v = ((unsigned)t < (unsigned)v) ? t : v;
  t = __builtin_amdgcn_update_dpp(v, v, 0x142, 0xf, 0xf, false);
  v = ((unsigned)t < (unsigned)v) ? t : v;
  t = __builtin_amdgcn_update_dpp(v, v, 0x143, 0xf, 0xf, false);
  v = ((unsigned)t < (unsigned)v) ? t : v;
  return (unsigned)__builtin_amdgcn_readlane(v, 63);   // lane 63 = global min
}

__launch_bounds__(NT, 1)
__global__ void hungarian_dpp(const float* __restrict__ outs,
                              const float* __restrict__ tgts,
                              int* __restrict__ out) {
  const int b = blockIdx.x;
  const int tid = threadIdx.x;
  const int lane = tid & 63;
  const int wv = tid >> 6;

  __shared__ CD colDat[Q + 1];      // colDat[j] = {u[p[j]], tx[p[j]-1], ty[p[j]-1]}
  __shared__ CD rowDat[T + 1];      // rowDat[r] = {u[r], tx[r-1], ty[r-1]}
  __shared__ short p[Q + 1];        // p[j]: row matched to col j (1-based), 0 free
  __shared__ short visCol[T + 8];   // visit chain: visCol[0]=0
  __shared__ double visD[T + 8];    // delta prefix sums (before step s)
  __shared__ unsigned phi[2][NW], plo[2][NW];   // per-wave partial keys (parity)
  __shared__ int pix[2][NW];                    // per-wave partial argmin j
  __shared__ int ansArr[T];
  __shared__ double s_rv[NW];
  __shared__ float sh_f;

  const size_t qbase = (size_t)b * Q;
  const size_t tbase = (size_t)b * T;

  // ---- stage per-thread column data (fixed mapping j = 1 + tid + k*256) ----
  float xs[KPT], qx[KPT], qy[KPT];
#pragma unroll
  for (int k = 0; k < KPT; ++k) {
    const size_t o = (qbase + tid + k * NT) * 3;
    xs[k] = outs[o];
    qx[k] = outs[o + 1];
    qy[k] = outs[o + 2];
  }
  {
    const size_t o = (tbase + tid) * 3;   // T == NT: one target per thread
    rowDat[tid + 1].tx = tgts[o + 1];
    rowDat[tid + 1].ty = tgts[o + 2];
    rowDat[tid + 1].u = 0.0;
    if (tid == 0) { rowDat[0].tx = 0.f; rowDat[0].ty = 0.f; rowDat[0].u = 0.0; }
  }

  // ---- softmax over Q logits (bitwise-identical to the R2-passing tree) ----
  float lmax = xs[0];
#pragma unroll
  for (int k = 1; k < KPT; ++k) lmax = fmaxf(lmax, xs[k]);
  for (int off = 32; off > 0; off >>= 1) lmax = fmaxf(lmax, __shfl_down(lmax, off));
  if ((tid & 63) == 0) s_rv[tid >> 6] = (double)lmax;
  __syncthreads();
  if (tid == 0) {
    float m2 = (float)s_rv[0];
    for (int w = 1; w < NW; ++w) m2 = fmaxf(m2, (float)s_rv[w]);
    sh_f = m2;
  }
  __syncthreads();
  const float smax = sh_f;
  float ex[KPT];
  float lsum = 0.f;
#pragma unroll
  for (int k = 0; k < KPT; ++k) { ex[k] = expf(xs[k] - smax); lsum += ex[k]; }
  for (int off = 32; off > 0; off >>= 1) lsum += __shfl_down(lsum, off);
  if ((tid & 63) == 0) s_rv[tid >> 6] = (double)lsum;
  __syncthreads();
  if (tid == 0) {
    float s2 = 0.f;
    for (int w = 0; w < NW; ++w) s2 += (float)s_rv[w];
    sh_f = s2;
  }
  __syncthreads();
  const float ssum = sh_f;
  float np_[KPT];
#pragma unroll
  for (int k = 0; k < KPT; ++k) np_[k] = -(ex[k] / ssum);

  // ---- init state ----
  for (int j = tid; j <= Q; j += NT) p[j] = 0;
  if (tid == 0) visCol[0] = 0;
  double vreg[KPT];   // v[j] for this thread's 8 columns
#pragma unroll
  for (int k = 0; k < KPT; ++k) vreg[k] = 0.0;
  __syncthreads();

  // ---- main loop over rows ----
  for (int i = 1; i <= T; ++i) {
    if (tid == 0) p[0] = (short)i;
    unsigned usedMask = 0;
    double D = 0.0;
    __syncthreads();            // Bs: prev epilogue writes drained
    double ui0 = rowDat[i].u;
    float tX = rowDat[i].tx, tY = rowDat[i].ty;
    int s = 0, S;

    for (;;) {
      // scan my 8 unused columns: cur = ((double)cf - u[i0]) - v[j]
      double bval = DINF;
      int bidx = 0x7fffffff;
#pragma unroll
      for (int k = 0; k < KPT; ++k) {
        const float cf = fabsf(qx[k] - tX) + fabsf(qy[k] - tY) + np_[k];
        double cur = ((double)cf - ui0) - vreg[k];
        if (usedMask & (1u << k)) cur = DINF;   // used => never wins strict <
        if (cur < bval) { bval = cur; bidx = 1 + tid + (k << 8); }
      }
      // monotonic u64 bit-key of the per-lane winner (canonicalize -0 -> +0)
      bval += 0.0;
      const long long bb = __double_as_longlong(bval);
      const unsigned long long key = (unsigned long long)bb ^
          ((bb < 0) ? 0xFFFFFFFFFFFFFFFFull : 0x8000000000000000ull);
      const unsigned khi = (unsigned)(key >> 32);
      const unsigned klo = (unsigned)key;

      // wave argmin: DPP min on hi32, ballot for winner, exact ties slow path
      const unsigned minhi = wave_min_u32_dpp(khi);
      const unsigned long long mask = __ballot(khi == minhi);
      unsigned wklo; int widx;
      if (__popcll(mask) == 1) {
        const int wl = (int)__ffsll(mask) - 1;
        wklo = (unsigned)__builtin_amdgcn_readlane((int)klo, wl);
        widx = __builtin_amdgcn_readlane(bidx, wl);
      } else {
        wklo = 0xffffffffu; widx = 0x7fffffff;
        unsigned long long mm = mask;
        while (mm) {
          const int l = (int)__ffsll(mm) - 1; mm &= mm - 1;
          const unsigned lo2 = (unsigned)__builtin_amdgcn_readlane((int)klo, l);
          const int ix2 = __builtin_amdgcn_readlane(bidx, l);
          if (lo2 < wklo || (lo2 == wklo && ix2 < widx)) { wklo = lo2; widx = ix2; }
        }
      }
      const int par = s & 1;
      if (lane == 0) { phi[par][wv] = minhi; plo[par][wv] = wklo; pix[par][wv] = widx; }
      if (tid == 0) visD[s] = D;   // prefix (deltas of steps < s)
      __syncthreads();            // the only per-step barrier

      // redundant cross-wave lexicographic reduce (broadcast LDS reads)
      unsigned long long bk = ((unsigned long long)phi[par][0] << 32) | plo[par][0];
      int bj = pix[par][0];
#pragma unroll
      for (int w = 1; w < NW; ++w) {
        const unsigned long long k2 =
            ((unsigned long long)phi[par][w] << 32) | plo[par][w];
        const int j2 = pix[par][w];
        if (k2 < bk || (k2 == bk && j2 < bj)) { bk = k2; bj = j2; }
      }
      // invert bit-key -> delta (bitwise identical on every thread)
      const long long db = (long long)((bk & 0x8000000000000000ull)
                                           ? (bk ^ 0x8000000000000000ull) : ~bk);
      D += __longlong_as_double(db);
      const int j1 = bj;          // selected column, 1-based
      if (tid == ((j1 - 1) & 255)) usedMask |= 1u << ((j1 - 1) >> 8);
      if (tid == 0) visCol[s + 1] = (short)j1;
      const int pj1 = (int)p[j1];     // parallel LDS reads: p[j1] ...
      const CD cd = colDat[j1];       // ... and its row's data (u, tx, ty)
      ++s;
      if (pj1 == 0) { S = s; break; }
      ui0 = cd.u; tX = cd.tx; tY = cd.ty;
    }

    // ---- epilogue: O(path) deferred updates (S <= 256 provable) ----
    __syncthreads();              // E0: in-search LDS traffic done
    const double Dfin = D;
    // snapshot pre-augment rows into registers
    const int rr0 = (tid < S) ? (int)p[(int)visCol[tid]] : 0;
    __syncthreads();              // E1
    if (tid < S) {
      const int cnew = (int)visCol[tid + 1];
      p[cnew] = (short)rr0;                       // augment
      const double unew = rowDat[rr0].u + (Dfin - visD[tid]);
      rowDat[rr0].u = unew;                       // u[row] += Dfin - visD[s]
      CD cd2; cd2.u = unew; cd2.tx = rowDat[rr0].tx; cd2.ty = rowDat[rr0].ty;
      colDat[cnew] = cd2;                         // refresh column cache
    }
    // v updates for used cols visCol[1..S-1] (owner thread applies)
    for (int sv = 1; sv < S; ++sv) {
      const int qv = (int)visCol[sv] - 1;
      if ((qv & 255) == tid) vreg[qv >> 8] -= (Dfin - visD[sv]);
    }
    // next Bs barrier orders these writes before the next search's reads
  }
  __syncthreads();

  // ---- extract assignment, rank-sort (distinct values), write int32 ----
  for (int j = 1 + tid; j <= Q; j += NT) {
    const int pi = (int)p[j];
    if (pi > 0) ansArr[pi - 1] = j - 1;
  }
  __syncthreads();
  const int a = ansArr[tid];
  int rank = 0;
  for (int t2 = 0; t2 < T; ++t2) rank += (ansArr[t2] < a) ? 1 : 0;
  out[(size_t)b * T + rank] = a;                      // row_ind (sorted query idx)
  out[(size_t)B * T + (size_t)b * T + rank] = tid;    // col_ind (target idx)
}

extern "C" void kernel_launch(void* const* d_in, const int* in_sizes, int n_in,
                              void* d_out, int out_size, void* d_ws, size_t ws_size,
                              hipStream_t stream) {
  const float* outs = (const float*)d_in[0];   // (8, 2048, 3) fp32
  const float* tgts = (const float*)d_in[1];   // (8, 256, 3) fp32
  int* out = (int*)d_out;                      // row_ind (8,256) ++ col_ind (8,256)
  hungarian_dpp<<<B, NT, 0, stream>>>(outs, tgts, out);
}